// Round 18
// baseline (355.459 us; speedup 1.0000x reference)
//
#include <hip/hip_runtime.h>
#include <stdint.h>

#define S_LEN 2048
#define NTOK  4096      // B*S
#define EMB   2048
#define NHEAD 32
#define HDIM  64
#define NKVH  8

typedef __bf16 bf16x8 __attribute__((ext_vector_type(8)));
typedef float  f32x4  __attribute__((ext_vector_type(4)));

#define AS1 __attribute__((address_space(1)))
#define AS3 __attribute__((address_space(3)))

#if __has_builtin(__builtin_amdgcn_exp2f)
#define EXP2(x) __builtin_amdgcn_exp2f(x)
#else
#define EXP2(x) exp2f(x)
#endif

// 0.125 * log2(e): folded into Q at RoPE so softmax runs in exp2 domain
#define QSCALE 0.1803368867f

__device__ __forceinline__ uint16_t f2bf(float f) {
  uint32_t u = __float_as_uint(f);
  u += 0x7fffu + ((u >> 16) & 1u);
  return (uint16_t)(u >> 16);
}
__device__ __forceinline__ float bf2f(uint16_t h) {
  return __uint_as_float(((uint32_t)h) << 16);
}
__device__ __forceinline__ void gld16(const void* g, void* l) {
  __builtin_amdgcn_global_load_lds((const AS1 uint32_t*)g, (AS3 uint32_t*)l, 16, 0, 0);
}
__device__ __forceinline__ f32x4 mfma16(bf16x8 a, bf16x8 b, f32x4 c) {
  return __builtin_amdgcn_mfma_f32_16x16x32_bf16(a, b, c, 0, 0, 0);
}

// ===== merged preprocessing: x->bf16 cvt + all 4 weight transposes, 1 launch =====
__global__ void k_preproc(const float* __restrict__ x, uint16_t* __restrict__ xb,
                          const float* __restrict__ wq, const float* __restrict__ wk,
                          const float* __restrict__ wv, const float* __restrict__ wo,
                          uint16_t* __restrict__ wT, uint16_t* __restrict__ woT) {
  __shared__ float tile[32][33];
  int bid = blockIdx.x;
  if (bid < 8192) {                     // ---- cvt x -> xb
    int i = (bid * 256 + threadIdx.x) * 4;
    float4 v = *(const float4*)(x + i);
    ushort4 o;
    o.x = f2bf(v.x); o.y = f2bf(v.y); o.z = f2bf(v.z); o.w = f2bf(v.w);
    *(ushort4*)(xb + i) = o;
    return;
  }
  bid -= 8192;
  const float* src; uint16_t* dst; int C, bx, by;
  if (bid < 4096)      { src = wq; dst = wT;                       C = 2048; bx = bid & 63; by = bid >> 6; }
  else if (bid < 5120) { src = wk; dst = wT + (size_t)2048 * 2048; C = 512;  bid -= 4096; bx = bid & 15; by = bid >> 4; }
  else if (bid < 6144) { src = wv; dst = wT + (size_t)2560 * 2048; C = 512;  bid -= 5120; bx = bid & 15; by = bid >> 4; }
  else                 { src = wo; dst = woT;                      C = 2048; bid -= 6144; bx = bid & 63; by = bid >> 6; }
  const int R = 2048;
  int c0 = bx * 32, r0 = by * 32;
  int tx = threadIdx.x & 31, ty = threadIdx.x >> 5;
#pragma unroll
  for (int j = 0; j < 32; j += 8)
    tile[ty + j][tx] = src[(size_t)(r0 + ty + j) * C + c0 + tx];
  __syncthreads();
#pragma unroll
  for (int j = 0; j < 32; j += 8)
    dst[(size_t)(c0 + ty + j) * R + r0 + tx] = f2bf(tile[tx][ty + j]);
}

// ===== 128x(N_REP*64) 3-phase GEMM, 256 thr, 2 blocks/CU (TLP structure) =====
template <int N_REP, typename OUT_T>
__global__ __launch_bounds__(256, 2) void k_gemm128(
    const uint16_t* __restrict__ A, const uint16_t* __restrict__ BT,
    OUT_T* __restrict__ C, int M, int N, int K) {
  constexpr int NF = 2 * N_REP;                 // per-wave B frags
  constexpr int LDSH = 8192 + N_REP * 4096;     // elements per buffer
  __shared__ uint16_t lds[2][LDSH];
  const int tid = threadIdx.x, lane = tid & 63, w = tid >> 6;
  const int wm = w >> 1, wn = w & 1;
  const int l16 = lane & 15, lg = lane >> 4;
  const int nbn = N / (N_REP * 64);
  const int nwg = gridDim.x, cpx = nwg >> 3;
  const int swz = ((int)blockIdx.x & 7) * cpx + ((int)blockIdx.x >> 3);
  const int bm = (swz / nbn) * 128, bn = (swz % nbn) * (N_REP * 64);

  f32x4 acc[4][NF] = {};

  const int srow = tid >> 3, sslot = tid & 7;
  const int schunk = (sslot ^ (srow & 7)) * 8;
  const uint16_t* Ag = A + (size_t)(bm + srow) * K + schunk;
  const uint16_t* Bg = BT + (size_t)(bn + srow) * K + schunk;

  auto stageA = [&](int d, int r, int k0) {
    gld16(Ag + (size_t)r * 32 * K + k0, &lds[d][r * 2048 + tid * 8]);
  };
  auto stageB = [&](int d, int r, int k0) {
    gld16(Bg + (size_t)r * 32 * K + k0, &lds[d][8192 + r * 2048 + tid * 8]);
  };
  auto lda = [&](int d, int mf, int s) -> bf16x8 {
    int row = wm * 64 + mf * 16 + l16;
    int slot = (s * 4 + lg) ^ (row & 7);
    return *(const bf16x8*)(&lds[d][row * 64 + slot * 8]);
  };
  auto ldb = [&](int d, int nf, int s) -> bf16x8 {
    int row = wn * (N_REP * 32) + nf * 16 + l16;
    int slot = (s * 4 + lg) ^ (row & 7);
    return *(const bf16x8*)(&lds[d][8192 + row * 64 + slot * 8]);
  };

  const int NT = K >> 6;
#pragma unroll
  for (int r = 0; r < 4; ++r) stageA(0, r, 0);
#pragma unroll
  for (int r = 0; r < 2 * N_REP; ++r) stageB(0, r, 0);
#pragma unroll
  for (int r = 0; r < 4; ++r) if (1 < NT) stageA(1, r, 64);
  asm volatile("s_waitcnt vmcnt(4)" ::: "memory");
  __builtin_amdgcn_s_barrier();

  for (int kt = 0; kt < NT; ++kt) {
    const int cur = kt & 1;
    const int nk0 = (kt + 1) << 6, nnk0 = (kt + 2) << 6;
    const bool m1 = (kt + 1 < NT), m2 = (kt + 2 < NT);
    bf16x8 a[2][2], a2[2][2], b[NF][2];
#pragma unroll
    for (int mi = 0; mi < 2; ++mi) { a[mi][0] = lda(cur, mi, 0); a[mi][1] = lda(cur, mi, 1); }
#pragma unroll
    for (int ni = 0; ni < NF; ++ni) { b[ni][0] = ldb(cur, ni, 0); b[ni][1] = ldb(cur, ni, 1); }
    if (m1) {
#pragma unroll
      for (int r = 0; r < 2 * N_REP; ++r) stageB(cur ^ 1, r, nk0);
    }
    __builtin_amdgcn_s_barrier();
    asm volatile("s_waitcnt lgkmcnt(0)" ::: "memory");
    __builtin_amdgcn_sched_barrier(0);
    __builtin_amdgcn_s_setprio(1);
#pragma unroll
    for (int mi = 0; mi < 2; ++mi)
#pragma unroll
      for (int ni = 0; ni < NF; ++ni) {
        acc[mi][ni] = mfma16(a[mi][0], b[ni][0], acc[mi][ni]);
        acc[mi][ni] = mfma16(a[mi][1], b[ni][1], acc[mi][ni]);
      }
    __builtin_amdgcn_s_setprio(0);
    __builtin_amdgcn_s_barrier();
#pragma unroll
    for (int mi = 0; mi < 2; ++mi) { a2[mi][0] = lda(cur, 2 + mi, 0); a2[mi][1] = lda(cur, 2 + mi, 1); }
    __builtin_amdgcn_s_barrier();
    asm volatile("s_waitcnt lgkmcnt(0)" ::: "memory");
    __builtin_amdgcn_sched_barrier(0);
    __builtin_amdgcn_s_setprio(1);
#pragma unroll
    for (int mi = 0; mi < 2; ++mi)
#pragma unroll
      for (int ni = 0; ni < N_REP; ++ni) {
        acc[2 + mi][ni] = mfma16(a2[mi][0], b[ni][0], acc[2 + mi][ni]);
        acc[2 + mi][ni] = mfma16(a2[mi][1], b[ni][1], acc[2 + mi][ni]);
      }
    __builtin_amdgcn_s_setprio(0);
    __builtin_amdgcn_s_barrier();
    if (m2) {
#pragma unroll
      for (int r = 0; r < 4; ++r) stageA(cur, r, nnk0);
    }
    __builtin_amdgcn_s_setprio(1);
#pragma unroll
    for (int mi = 0; mi < 2; ++mi)
#pragma unroll
      for (int ni = N_REP; ni < NF; ++ni) {
        acc[2 + mi][ni] = mfma16(a2[mi][0], b[ni][0], acc[2 + mi][ni]);
        acc[2 + mi][ni] = mfma16(a2[mi][1], b[ni][1], acc[2 + mi][ni]);
      }
    __builtin_amdgcn_s_setprio(0);
    if (m2) { asm volatile("s_waitcnt vmcnt(4)" ::: "memory"); }
    else    { asm volatile("s_waitcnt vmcnt(0)" ::: "memory"); }
    __builtin_amdgcn_s_barrier();
  }
#pragma unroll
  for (int mf = 0; mf < 4; ++mf)
#pragma unroll
    for (int nf = 0; nf < NF; ++nf)
#pragma unroll
      for (int r = 0; r < 4; ++r) {
        int row = bm + wm * 64 + mf * 16 + lg * 4 + r;
        int col = bn + wn * (N_REP * 32) + nf * 16 + l16;
        float v = acc[mf][nf][r];
        if constexpr (sizeof(OUT_T) == 4) C[(size_t)row * N + col] = v;
        else                              C[(size_t)row * N + col] = f2bf(v);
      }
}

// ===== merged RoPE (Q+K) + V transpose, 1 launch (both read qkvb) =====
// blocks [0,5120): rope 8-elem chunks; [5120,+2048): V 32x32 transpose tiles
__global__ void k_rope_tv(const uint16_t* __restrict__ qkv, const float* __restrict__ cosT,
                          const float* __restrict__ sinT, uint16_t* __restrict__ qb,
                          uint16_t* __restrict__ kb, uint16_t* __restrict__ vT) {
  int bid = blockIdx.x;
  if (bid < 5120) {                     // ---- RoPE Q+K
    int idx = bid * 256 + threadIdx.x;
    int row = idx / 320;
    int col8 = (idx - row * 320) * 8;
    int s = row & (S_LEN - 1);
    union { uint4 q; uint16_t u[8]; } in;
    in.q = *(const uint4*)(qkv + (size_t)row * 3072 + col8);
    const bool isQ = (col8 < 2048);
    int cc = isQ ? col8 : col8 - 2048;
    int i0 = (cc & 63) >> 1;
    float4 c4 = *(const float4*)(cosT + s * 32 + i0);
    float4 s4 = *(const float4*)(sinT + s * 32 + i0);
    if (isQ) {
      c4.x *= QSCALE; c4.y *= QSCALE; c4.z *= QSCALE; c4.w *= QSCALE;
      s4.x *= QSCALE; s4.y *= QSCALE; s4.z *= QSCALE; s4.w *= QSCALE;
    }
    float cs[4] = {c4.x, c4.y, c4.z, c4.w};
    float sn[4] = {s4.x, s4.y, s4.z, s4.w};
    union { uint4 q; uint16_t u[8]; } out;
#pragma unroll
    for (int p = 0; p < 4; ++p) {
      float t1 = bf2f(in.u[2 * p]), t2 = bf2f(in.u[2 * p + 1]);
      out.u[2 * p]     = f2bf(t1 * cs[p] - t2 * sn[p]);
      out.u[2 * p + 1] = f2bf(t1 * sn[p] + t2 * cs[p]);
    }
    if (isQ) *(uint4*)(qb + (size_t)row * 2048 + col8) = out.q;
    else     *(uint4*)(kb + (size_t)row * 512 + cc)    = out.q;
    return;
  }
  // ---- V transpose: vT[(b*8+kvh)*64+hd][S]
  __shared__ uint16_t tile[32][33];
  bid -= 5120;                          // 0..2047 = 64 s-tiles x 2 hd-tiles x 16 bh
  int s0 = (bid & 63) * 32, hd0 = ((bid >> 6) & 1) * 32, bh = bid >> 7;
  int b = bh >> 3, kvh = bh & 7;
  int tx = threadIdx.x & 31, ty = threadIdx.x >> 5;
#pragma unroll
  for (int j = 0; j < 32; j += 8)
    tile[ty + j][tx] =
        qkv[((size_t)b * S_LEN + s0 + ty + j) * 3072 + 2560 + kvh * 64 + hd0 + tx];
  __syncthreads();
#pragma unroll
  for (int j = 0; j < 32; j += 8)
    vT[((size_t)bh * 64 + hd0 + ty + j) * S_LEN + s0 + tx] = tile[tx][ty + j];
}

// --- per-tile compute, qc=4 (64 q-rows/wave): QK^T + softmax + PV ---
// K/V frags loaded once per tile, reused by 4 q-chunks (2x the R17 reuse).
template <bool MASKED>
__device__ __forceinline__ void tile_compute4(
    const uint16_t* Kc, const uint16_t* Vc, const bf16x8 qf[4][2], bf16x8 onesv,
    int l16, int lg, int kv0, int qb0,
    float m_r[4], f32x4 lacc[4], f32x4 acc[4][4]) {
  f32x4 st[4][4] = {};
  __builtin_amdgcn_s_setprio(1);
#pragma unroll
  for (int c = 0; c < 4; ++c) {
    int row = c * 16 + l16, sw = row & 7;
    bf16x8 ka  = *(const bf16x8*)(Kc + row * 64 + ((lg ^ sw) * 8));
    bf16x8 kb2 = *(const bf16x8*)(Kc + row * 64 + (((4 | lg) ^ sw) * 8));
#pragma unroll
    for (int qc = 0; qc < 4; ++qc) {
      st[qc][c] = mfma16(ka,  qf[qc][0], st[qc][c]);
      st[qc][c] = mfma16(kb2, qf[qc][1], st[qc][c]);
    }
  }
  __builtin_amdgcn_s_setprio(0);
  bf16x8 pu[4][2];
#pragma unroll
  for (int qc = 0; qc < 4; ++qc) {
    const int qrow = qb0 + qc * 16 + l16;
    float sv[4][4];
#pragma unroll
    for (int c = 0; c < 4; ++c)
#pragma unroll
      for (int r = 0; r < 4; ++r) {
        float s = st[qc][c][r];
        if (MASKED && (kv0 + c * 16 + lg * 4 + r > qrow)) s = -1e30f;
        sv[c][r] = s;
      }
    // lane-partial max via v_max3 chain
    float mx = fmaxf(sv[0][0], sv[0][1]);
    mx = fmaxf(fmaxf(mx, sv[0][2]), sv[0][3]);
    mx = fmaxf(fmaxf(mx, sv[1][0]), sv[1][1]);
    mx = fmaxf(fmaxf(mx, sv[1][2]), sv[1][3]);
    mx = fmaxf(fmaxf(mx, sv[2][0]), sv[2][1]);
    mx = fmaxf(fmaxf(mx, sv[2][2]), sv[2][3]);
    mx = fmaxf(fmaxf(mx, sv[3][0]), sv[3][1]);
    mx = fmaxf(fmaxf(mx, sv[3][2]), sv[3][3]);
    if (!__all(mx - m_r[qc] <= 8.0f)) {   // lazy full reduce + rescale (rare)
      float mxf = fmaxf(mx, __shfl_xor(mx, 16));
      mxf = fmaxf(mxf, __shfl_xor(mxf, 32));
      float m_new = fmaxf(m_r[qc], mxf);
      float alpha = EXP2(m_r[qc] - m_new);
      float al[4];
#pragma unroll
      for (int r = 0; r < 4; ++r) al[r] = __shfl(alpha, lg * 4 + r);
#pragma unroll
      for (int n = 0; n < 4; ++n)
#pragma unroll
        for (int r = 0; r < 4; ++r) acc[qc][n][r] *= al[r];
#pragma unroll
      for (int r = 0; r < 4; ++r) lacc[qc][r] *= al[r];
      m_r[qc] = m_new;
    }
    float pf[4][4];
#pragma unroll
    for (int c = 0; c < 4; ++c)
#pragma unroll
      for (int r = 0; r < 4; ++r)
        pf[c][r] = EXP2(sv[c][r] - m_r[qc]);
#pragma unroll
    for (int cc = 0; cc < 2; ++cc)
#pragma unroll
      for (int e = 0; e < 8; ++e)
        ((__bf16*)&pu[qc][cc])[e] = (__bf16)pf[cc * 2 + (e >> 2)][e & 3];
  }
  // PV: V-frags loaded once, reused by all 4 qc; lacc via ones-MFMA
  __builtin_amdgcn_s_setprio(1);
#pragma unroll
  for (int cc = 0; cc < 2; ++cc) {
#pragma unroll
    for (int qc = 0; qc < 4; ++qc) lacc[qc] = mfma16(pu[qc][cc], onesv, lacc[qc]);
#pragma unroll
    for (int n = 0; n < 4; ++n) {
      int row = n * 16 + l16, sw2 = row & 7;
      int k0 = cc * 32 + lg * 4, k1 = k0 + 16;
      const char* base = (const char*)Vc + row * 128;
      union { uint64_t q[2]; bf16x8 v; } vu;
      vu.q[0] = *(const uint64_t*)(base + (((k0 >> 3) ^ sw2) << 4) + ((k0 & 7) << 1));
      vu.q[1] = *(const uint64_t*)(base + (((k1 >> 3) ^ sw2) << 4) + ((k1 & 7) << 1));
#pragma unroll
      for (int qc = 0; qc < 4; ++qc) acc[qc][n] = mfma16(pu[qc][cc], vu.v, acc[qc][n]);
    }
  }
  __builtin_amdgcn_s_setprio(0);
}

// ---- flash v8: qc=4 (wave = head x 64 q-rows); 512 blocks = 2/CU exact;
// complementary-j pairing (j + (31-j) = const work per CU); ring-3 LDS,
// prefetch dist 2, counted vmcnt(4). VGPR ~230 under (256,2) cap.
__global__ __launch_bounds__(256, 2) void k_flash(
    const uint16_t* __restrict__ Qb, const uint16_t* __restrict__ Kb,
    const uint16_t* __restrict__ VT, uint16_t* __restrict__ Ob) {
  __shared__ uint16_t Ks[3][4096];   // [kv][hd], chunk^(kv&7)
  __shared__ uint16_t Vs[3][4096];   // [hd][kv], chunk^(hd&7)
  const int lidx = blockIdx.x;       // 0..511
  const int jj = lidx & 31;
  const int j = (lidx < 256) ? 31 - jj : jj;   // 64-row q-tile index 0..31
  const int gb = lidx >> 5;                    // 0..15 (g,b); gb repeats per half
  const int g = gb & 7, b = (gb >> 3) & 1;
  const int tid = threadIdx.x, lane = tid & 63, w = tid >> 6;
  const int l16 = lane & 15, lg = lane >> 4;
  const int h = g * 4 + w;                     // wave's head
  const int qb0 = j * 64;                      // wave's 64-row q base

  bf16x8 qf[4][2];
#pragma unroll
  for (int qc = 0; qc < 4; ++qc) {
    const size_t tokq = (size_t)b * S_LEN + qb0 + qc * 16 + l16;
    qf[qc][0] = *(const bf16x8*)(Qb + tokq * 2048 + h * 64 + lg * 8);
    qf[qc][1] = *(const bf16x8*)(Qb + tokq * 2048 + h * 64 + 32 + lg * 8);
  }
  bf16x8 onesv;
#pragma unroll
  for (int e = 0; e < 8; ++e) ((__bf16*)&onesv)[e] = (__bf16)1.0f;

  const int srow = tid >> 3, shc = tid & 7;
  const int swz = (shc ^ (srow & 7)) * 8;
  const uint16_t* Kg = Kb + ((size_t)b * S_LEN + srow) * 512 + g * 64 + swz;
  const uint16_t* Vg = VT + ((size_t)(b * 8 + g) * 64 + srow) * S_LEN + swz;

  float m_r[4] = {-1e30f, -1e30f, -1e30f, -1e30f};
  f32x4 lacc[4] = {};
  f32x4 acc[4][4] = {};
  const int nt = j + 1;                        // KV tiles needed (64 rows span)

  auto stage = [&](int t, int buf) {
    const size_t kv0 = (size_t)t * 64;
    uint16_t* kd = &Ks[buf][tid * 8];
    uint16_t* vd = &Vs[buf][tid * 8];
    gld16(Kg + kv0 * 512, kd);
    gld16(Kg + (kv0 + 32) * 512, kd + 2048);
    gld16(Vg + kv0, vd);
    gld16(Vg + kv0 + (size_t)32 * S_LEN, vd + 2048);
  };

  stage(0, 0);
  stage(nt > 1 ? 1 : 0, 1);

  int cur = 0;
  for (int t = 0; t < nt; ++t) {
    asm volatile("s_waitcnt vmcnt(4)" ::: "memory");
    __builtin_amdgcn_s_barrier();
    {
      int ts = t + 2 < nt ? t + 2 : nt - 1;
      int bufn = cur + 2; if (bufn >= 3) bufn -= 3;
      stage(ts, bufn);
    }
    if (t == nt - 1)
      tile_compute4<true >(Ks[cur], Vs[cur], qf, onesv, l16, lg, t * 64, qb0, m_r, lacc, acc);
    else
      tile_compute4<false>(Ks[cur], Vs[cur], qf, onesv, l16, lg, t * 64, qb0, m_r, lacc, acc);
    cur = cur + 1 < 3 ? cur + 1 : 0;
  }
#pragma unroll
  for (int qc = 0; qc < 4; ++qc) {
    float li[4];
#pragma unroll
    for (int r = 0; r < 4; ++r) li[r] = 1.0f / lacc[qc][r];
#pragma unroll
    for (int n = 0; n < 4; ++n)
#pragma unroll
      for (int r = 0; r < 4; ++r) {
        int qo = qb0 + qc * 16 + lg * 4 + r;
        Ob[((size_t)b * S_LEN + qo) * 2048 + h * 64 + n * 16 + l16] =
            f2bf(acc[qc][n][r] * li[r]);
      }
  }
}

extern "C" void kernel_launch(void* const* d_in, const int* in_sizes, int n_in,
                              void* d_out, int out_size, void* d_ws, size_t ws_size,
                              hipStream_t stream) {
  const float* x    = (const float*)d_in[0];
  const float* cosT = (const float*)d_in[1];
  const float* sinT = (const float*)d_in[2];
  const float* wq   = (const float*)d_in[4];
  const float* wk   = (const float*)d_in[5];
  const float* wv   = (const float*)d_in[6];
  const float* wo   = (const float*)d_in[7];
  float* out = (float*)d_out;

  char* ws = (char*)d_ws;
  size_t off = 0;
  auto alloc = [&](size_t bytes) {
    void* p = ws + off;
    off += (bytes + 255) & ~(size_t)255;
    return p;
  };
  uint16_t* xb   = (uint16_t*)alloc((size_t)NTOK * EMB * 2);
  uint16_t* wT   = (uint16_t*)alloc((size_t)3072 * 2048 * 2);
  uint16_t* woT  = (uint16_t*)alloc((size_t)2048 * 2048 * 2);
  uint16_t* qkvb = (uint16_t*)alloc((size_t)NTOK * 3072 * 2);
  uint16_t* qb   = (uint16_t*)alloc((size_t)NTOK * 2048 * 2);
  uint16_t* kb   = (uint16_t*)alloc((size_t)NTOK * 512 * 2);
  uint16_t* vT   = (uint16_t*)alloc((size_t)NTOK * 512 * 2);
  uint16_t* ob   = xb;                 // xb dead after QKV GEMM

  // merged: cvt (8192 blocks) + 4 weight transposes (10240 tile-blocks)
  k_preproc<<<18432, 256, 0, stream>>>(x, xb, wq, wk, wv, wo, wT, woT);

  // QKV: 128x192 tile -> 512 blocks = 2/CU (TLP structure)
  k_gemm128<3, uint16_t><<<512, 256, 0, stream>>>(xb, wT, qkvb, 4096, 3072, 2048);
  // merged RoPE + V-transpose (both read qkvb)
  k_rope_tv<<<5120 + 2048, 256, 0, stream>>>(qkvb, cosT, sinT, qb, kb, vT);
  k_flash<<<dim3(512), 256, 0, stream>>>(qb, kb, vT, ob);
  // out-proj: 128x128 tile, 512 blocks = 2/CU
  k_gemm128<2, float><<<512, 256, 0, stream>>>(ob, woT, out, 4096, 2048, 2048);
}

// Round 19
// 164.266 us; speedup vs baseline: 2.1639x; 2.1639x over previous
//
#include <hip/hip_runtime.h>
#include <stdint.h>

#define S_LEN 2048
#define NTOK  4096      // B*S
#define EMB   2048
#define NHEAD 32
#define HDIM  64
#define NKVH  8

typedef __bf16 bf16x8 __attribute__((ext_vector_type(8)));
typedef float  f32x4  __attribute__((ext_vector_type(4)));

#define AS1 __attribute__((address_space(1)))
#define AS3 __attribute__((address_space(3)))

#if __has_builtin(__builtin_amdgcn_exp2f)
#define EXP2(x) __builtin_amdgcn_exp2f(x)
#else
#define EXP2(x) exp2f(x)
#endif

// 0.125 * log2(e): folded into Q at RoPE so softmax runs in exp2 domain
#define QSCALE 0.1803368867f

__device__ __forceinline__ uint16_t f2bf(float f) {
  uint32_t u = __float_as_uint(f);
  u += 0x7fffu + ((u >> 16) & 1u);
  return (uint16_t)(u >> 16);
}
__device__ __forceinline__ float bf2f(uint16_t h) {
  return __uint_as_float(((uint32_t)h) << 16);
}
__device__ __forceinline__ void gld16(const void* g, void* l) {
  __builtin_amdgcn_global_load_lds((const AS1 uint32_t*)g, (AS3 uint32_t*)l, 16, 0, 0);
}
__device__ __forceinline__ f32x4 mfma16(bf16x8 a, bf16x8 b, f32x4 c) {
  return __builtin_amdgcn_mfma_f32_16x16x32_bf16(a, b, c, 0, 0, 0);
}

// ===== merged preprocessing: x->bf16 cvt + all 4 weight transposes, 1 launch =====
__global__ void k_preproc(const float* __restrict__ x, uint16_t* __restrict__ xb,
                          const float* __restrict__ wq, const float* __restrict__ wk,
                          const float* __restrict__ wv, const float* __restrict__ wo,
                          uint16_t* __restrict__ wT, uint16_t* __restrict__ woT) {
  __shared__ float tile[32][33];
  int bid = blockIdx.x;
  if (bid < 8192) {                     // ---- cvt x -> xb
    int i = (bid * 256 + threadIdx.x) * 4;
    float4 v = *(const float4*)(x + i);
    ushort4 o;
    o.x = f2bf(v.x); o.y = f2bf(v.y); o.z = f2bf(v.z); o.w = f2bf(v.w);
    *(ushort4*)(xb + i) = o;
    return;
  }
  bid -= 8192;
  const float* src; uint16_t* dst; int C, bx, by;
  if (bid < 4096)      { src = wq; dst = wT;                       C = 2048; bx = bid & 63; by = bid >> 6; }
  else if (bid < 5120) { src = wk; dst = wT + (size_t)2048 * 2048; C = 512;  bid -= 4096; bx = bid & 15; by = bid >> 4; }
  else if (bid < 6144) { src = wv; dst = wT + (size_t)2560 * 2048; C = 512;  bid -= 5120; bx = bid & 15; by = bid >> 4; }
  else                 { src = wo; dst = woT;                      C = 2048; bid -= 6144; bx = bid & 63; by = bid >> 6; }
  const int R = 2048;
  int c0 = bx * 32, r0 = by * 32;
  int tx = threadIdx.x & 31, ty = threadIdx.x >> 5;
#pragma unroll
  for (int j = 0; j < 32; j += 8)
    tile[ty + j][tx] = src[(size_t)(r0 + ty + j) * C + c0 + tx];
  __syncthreads();
#pragma unroll
  for (int j = 0; j < 32; j += 8)
    dst[(size_t)(c0 + ty + j) * R + r0 + tx] = f2bf(tile[tx][ty + j]);
}

// -- transpose V (bf16) from qkvb cols [2560,3072): -> vT [(b*8+kvh)*64+hd][S] --
__global__ void k_transpose_v(const uint16_t* __restrict__ qkv, uint16_t* __restrict__ out) {
  __shared__ uint16_t tile[32][33];
  int s0 = blockIdx.x * 32, hd0 = blockIdx.y * 32, bh = blockIdx.z;
  int b = bh >> 3, kvh = bh & 7;
  int tx = threadIdx.x & 31, ty = threadIdx.x >> 5;
#pragma unroll
  for (int j = 0; j < 32; j += 8)
    tile[ty + j][tx] =
        qkv[((size_t)b * S_LEN + s0 + ty + j) * 3072 + 2560 + kvh * 64 + hd0 + tx];
  __syncthreads();
#pragma unroll
  for (int j = 0; j < 32; j += 8)
    out[((size_t)bh * 64 + hd0 + ty + j) * S_LEN + s0 + tx] = tile[tx][ty + j];
}

// ===== 128x(N_REP*64) 3-phase GEMM, 256 thr, 2 blocks/CU (TLP structure) =====
template <int N_REP, typename OUT_T>
__global__ __launch_bounds__(256, 2) void k_gemm128(
    const uint16_t* __restrict__ A, const uint16_t* __restrict__ BT,
    OUT_T* __restrict__ C, int M, int N, int K) {
  constexpr int NF = 2 * N_REP;                 // per-wave B frags
  constexpr int LDSH = 8192 + N_REP * 4096;     // elements per buffer
  __shared__ uint16_t lds[2][LDSH];
  const int tid = threadIdx.x, lane = tid & 63, w = tid >> 6;
  const int wm = w >> 1, wn = w & 1;
  const int l16 = lane & 15, lg = lane >> 4;
  const int nbn = N / (N_REP * 64);
  const int nwg = gridDim.x, cpx = nwg >> 3;
  const int swz = ((int)blockIdx.x & 7) * cpx + ((int)blockIdx.x >> 3);
  const int bm = (swz / nbn) * 128, bn = (swz % nbn) * (N_REP * 64);

  f32x4 acc[4][NF] = {};

  const int srow = tid >> 3, sslot = tid & 7;
  const int schunk = (sslot ^ (srow & 7)) * 8;
  const uint16_t* Ag = A + (size_t)(bm + srow) * K + schunk;
  const uint16_t* Bg = BT + (size_t)(bn + srow) * K + schunk;

  auto stageA = [&](int d, int r, int k0) {
    gld16(Ag + (size_t)r * 32 * K + k0, &lds[d][r * 2048 + tid * 8]);
  };
  auto stageB = [&](int d, int r, int k0) {
    gld16(Bg + (size_t)r * 32 * K + k0, &lds[d][8192 + r * 2048 + tid * 8]);
  };
  auto lda = [&](int d, int mf, int s) -> bf16x8 {
    int row = wm * 64 + mf * 16 + l16;
    int slot = (s * 4 + lg) ^ (row & 7);
    return *(const bf16x8*)(&lds[d][row * 64 + slot * 8]);
  };
  auto ldb = [&](int d, int nf, int s) -> bf16x8 {
    int row = wn * (N_REP * 32) + nf * 16 + l16;
    int slot = (s * 4 + lg) ^ (row & 7);
    return *(const bf16x8*)(&lds[d][8192 + row * 64 + slot * 8]);
  };

  const int NT = K >> 6;
#pragma unroll
  for (int r = 0; r < 4; ++r) stageA(0, r, 0);
#pragma unroll
  for (int r = 0; r < 2 * N_REP; ++r) stageB(0, r, 0);
#pragma unroll
  for (int r = 0; r < 4; ++r) if (1 < NT) stageA(1, r, 64);
  asm volatile("s_waitcnt vmcnt(4)" ::: "memory");
  __builtin_amdgcn_s_barrier();

  for (int kt = 0; kt < NT; ++kt) {
    const int cur = kt & 1;
    const int nk0 = (kt + 1) << 6, nnk0 = (kt + 2) << 6;
    const bool m1 = (kt + 1 < NT), m2 = (kt + 2 < NT);
    bf16x8 a[2][2], a2[2][2], b[NF][2];
    // ph0: read a(mf0,1) + all b; stage B(kt+1); MFMA mf01 x all nf
#pragma unroll
    for (int mi = 0; mi < 2; ++mi) { a[mi][0] = lda(cur, mi, 0); a[mi][1] = lda(cur, mi, 1); }
#pragma unroll
    for (int ni = 0; ni < NF; ++ni) { b[ni][0] = ldb(cur, ni, 0); b[ni][1] = ldb(cur, ni, 1); }
    if (m1) {
#pragma unroll
      for (int r = 0; r < 2 * N_REP; ++r) stageB(cur ^ 1, r, nk0);
    }
    __builtin_amdgcn_s_barrier();
    asm volatile("s_waitcnt lgkmcnt(0)" ::: "memory");
    __builtin_amdgcn_sched_barrier(0);
    __builtin_amdgcn_s_setprio(1);
#pragma unroll
    for (int mi = 0; mi < 2; ++mi)
#pragma unroll
      for (int ni = 0; ni < NF; ++ni) {
        acc[mi][ni] = mfma16(a[mi][0], b[ni][0], acc[mi][ni]);
        acc[mi][ni] = mfma16(a[mi][1], b[ni][1], acc[mi][ni]);
      }
    __builtin_amdgcn_s_setprio(0);
    __builtin_amdgcn_s_barrier();
    // ph1: read a(mf2,3); MFMA mf23 x nf[0,N_REP)
#pragma unroll
    for (int mi = 0; mi < 2; ++mi) { a2[mi][0] = lda(cur, 2 + mi, 0); a2[mi][1] = lda(cur, 2 + mi, 1); }
    __builtin_amdgcn_s_barrier();
    asm volatile("s_waitcnt lgkmcnt(0)" ::: "memory");
    __builtin_amdgcn_sched_barrier(0);
    __builtin_amdgcn_s_setprio(1);
#pragma unroll
    for (int mi = 0; mi < 2; ++mi)
#pragma unroll
      for (int ni = 0; ni < N_REP; ++ni) {
        acc[2 + mi][ni] = mfma16(a2[mi][0], b[ni][0], acc[2 + mi][ni]);
        acc[2 + mi][ni] = mfma16(a2[mi][1], b[ni][1], acc[2 + mi][ni]);
      }
    __builtin_amdgcn_s_setprio(0);
    __builtin_amdgcn_s_barrier();   // all A reads of buf[cur] complete
    // ph2: stage A(kt+2) into buf[cur] (safe); MFMA mf23 x nf[N_REP,NF)
    if (m2) {
#pragma unroll
      for (int r = 0; r < 4; ++r) stageA(cur, r, nnk0);
    }
    __builtin_amdgcn_s_setprio(1);
#pragma unroll
    for (int mi = 0; mi < 2; ++mi)
#pragma unroll
      for (int ni = N_REP; ni < NF; ++ni) {
        acc[2 + mi][ni] = mfma16(a2[mi][0], b[ni][0], acc[2 + mi][ni]);
        acc[2 + mi][ni] = mfma16(a2[mi][1], b[ni][1], acc[2 + mi][ni]);
      }
    __builtin_amdgcn_s_setprio(0);
    if (m2) { asm volatile("s_waitcnt vmcnt(4)" ::: "memory"); }
    else    { asm volatile("s_waitcnt vmcnt(0)" ::: "memory"); }
    __builtin_amdgcn_s_barrier();
  }
#pragma unroll
  for (int mf = 0; mf < 4; ++mf)
#pragma unroll
    for (int nf = 0; nf < NF; ++nf)
#pragma unroll
      for (int r = 0; r < 4; ++r) {
        int row = bm + wm * 64 + mf * 16 + lg * 4 + r;
        int col = bn + wn * (N_REP * 32) + nf * 16 + l16;
        float v = acc[mf][nf][r];
        if constexpr (sizeof(OUT_T) == 4) C[(size_t)row * N + col] = v;
        else                              C[(size_t)row * N + col] = f2bf(v);
      }
}

// ----- RoPE + split, Q+K only; 16B/lane (4 pairs/thread), float4 cos/sin -----
__global__ void k_rope(const uint16_t* __restrict__ qkv, const float* __restrict__ cosT,
                       const float* __restrict__ sinT, uint16_t* __restrict__ qb,
                       uint16_t* __restrict__ kb) {
  int idx = blockIdx.x * 256 + threadIdx.x;   // NTOK*320 chunks of 8 elems
  int row = idx / 320;
  int col8 = (idx - row * 320) * 8;           // elem offset in [0,2560), 8-aligned
  int s = row & (S_LEN - 1);
  union { uint4 q; uint16_t u[8]; } in;
  in.q = *(const uint4*)(qkv + (size_t)row * 3072 + col8);
  const bool isQ = (col8 < 2048);
  int cc = isQ ? col8 : col8 - 2048;
  int i0 = (cc & 63) >> 1;                    // 4 consecutive freq indices
  float4 c4 = *(const float4*)(cosT + s * 32 + i0);
  float4 s4 = *(const float4*)(sinT + s * 32 + i0);
  if (isQ) {
    c4.x *= QSCALE; c4.y *= QSCALE; c4.z *= QSCALE; c4.w *= QSCALE;
    s4.x *= QSCALE; s4.y *= QSCALE; s4.z *= QSCALE; s4.w *= QSCALE;
  }
  float cs[4] = {c4.x, c4.y, c4.z, c4.w};
  float sn[4] = {s4.x, s4.y, s4.z, s4.w};
  union { uint4 q; uint16_t u[8]; } out;
#pragma unroll
  for (int p = 0; p < 4; ++p) {
    float t1 = bf2f(in.u[2 * p]), t2 = bf2f(in.u[2 * p + 1]);
    out.u[2 * p]     = f2bf(t1 * cs[p] - t2 * sn[p]);
    out.u[2 * p + 1] = f2bf(t1 * sn[p] + t2 * cs[p]);
  }
  if (isQ) *(uint4*)(qb + (size_t)row * 2048 + col8) = out.q;
  else     *(uint4*)(kb + (size_t)row * 512 + cc)    = out.q;
}

// ------- per-tile compute: QK^T + softmax + PV; lazy max (max3 chain) -------
template <bool MASKED>
__device__ __forceinline__ void tile_compute(
    const uint16_t* Kc, const uint16_t* Vc, const bf16x8 qf[2][2], bf16x8 onesv,
    int l16, int lg, int kv0, int qb0,
    float m_r[2], f32x4 lacc[2], f32x4 acc[2][4]) {
  f32x4 st[2][4] = {};
  __builtin_amdgcn_s_setprio(1);
#pragma unroll
  for (int c = 0; c < 4; ++c) {
    int row = c * 16 + l16, sw = row & 7;
    bf16x8 ka  = *(const bf16x8*)(Kc + row * 64 + ((lg ^ sw) * 8));
    bf16x8 kb2 = *(const bf16x8*)(Kc + row * 64 + (((4 | lg) ^ sw) * 8));
#pragma unroll
    for (int qc = 0; qc < 2; ++qc) {
      st[qc][c] = mfma16(ka,  qf[qc][0], st[qc][c]);
      st[qc][c] = mfma16(kb2, qf[qc][1], st[qc][c]);
    }
  }
  __builtin_amdgcn_s_setprio(0);
  bf16x8 pu[2][2];
#pragma unroll
  for (int qc = 0; qc < 2; ++qc) {
    const int qrow = qb0 + qc * 16 + l16;
    float sv[4][4];
#pragma unroll
    for (int c = 0; c < 4; ++c)
#pragma unroll
      for (int r = 0; r < 4; ++r) {
        float s = st[qc][c][r];
        if (MASKED && (kv0 + c * 16 + lg * 4 + r > qrow)) s = -1e30f;
        sv[c][r] = s;
      }
    // lane-partial max via v_max3 chain (8 ops vs 15-op pairwise tree)
    float mx = fmaxf(sv[0][0], sv[0][1]);
    mx = fmaxf(fmaxf(mx, sv[0][2]), sv[0][3]);
    mx = fmaxf(fmaxf(mx, sv[1][0]), sv[1][1]);
    mx = fmaxf(fmaxf(mx, sv[1][2]), sv[1][3]);
    mx = fmaxf(fmaxf(mx, sv[2][0]), sv[2][1]);
    mx = fmaxf(fmaxf(mx, sv[2][2]), sv[2][3]);
    mx = fmaxf(fmaxf(mx, sv[3][0]), sv[3][1]);
    mx = fmaxf(fmaxf(mx, sv[3][2]), sv[3][3]);
    if (!__all(mx - m_r[qc] <= 8.0f)) {   // violated -> full reduce + rescale
      float mxf = fmaxf(mx, __shfl_xor(mx, 16));
      mxf = fmaxf(mxf, __shfl_xor(mxf, 32));
      float m_new = fmaxf(m_r[qc], mxf);
      float alpha = EXP2(m_r[qc] - m_new);
      float al[4];
#pragma unroll
      for (int r = 0; r < 4; ++r) al[r] = __shfl(alpha, lg * 4 + r);
#pragma unroll
      for (int n = 0; n < 4; ++n)
#pragma unroll
        for (int r = 0; r < 4; ++r) acc[qc][n][r] *= al[r];
#pragma unroll
      for (int r = 0; r < 4; ++r) lacc[qc][r] *= al[r];
      m_r[qc] = m_new;
    }
    float pf[4][4];
#pragma unroll
    for (int c = 0; c < 4; ++c)
#pragma unroll
      for (int r = 0; r < 4; ++r)
        pf[c][r] = EXP2(sv[c][r] - m_r[qc]);
#pragma unroll
    for (int cc = 0; cc < 2; ++cc)
#pragma unroll
      for (int e = 0; e < 8; ++e)
        ((__bf16*)&pu[qc][cc])[e] = (__bf16)pf[cc * 2 + (e >> 2)][e & 3];
  }
  // PV: V-frags loaded once, reused by both qc; lacc via ones-MFMA (acc layout)
  __builtin_amdgcn_s_setprio(1);
#pragma unroll
  for (int cc = 0; cc < 2; ++cc) {
    lacc[0] = mfma16(pu[0][cc], onesv, lacc[0]);
    lacc[1] = mfma16(pu[1][cc], onesv, lacc[1]);
#pragma unroll
    for (int n = 0; n < 4; ++n) {
      int row = n * 16 + l16, sw2 = row & 7;
      int k0 = cc * 32 + lg * 4, k1 = k0 + 16;
      const char* base = (const char*)Vc + row * 128;
      union { uint64_t q[2]; bf16x8 v; } vu;
      vu.q[0] = *(const uint64_t*)(base + (((k0 >> 3) ^ sw2) << 4) + ((k0 & 7) << 1));
      vu.q[1] = *(const uint64_t*)(base + (((k1 >> 3) ^ sw2) << 4) + ((k1 & 7) << 1));
      acc[0][n] = mfma16(pu[0][cc], vu.v, acc[0][n]);
      acc[1][n] = mfma16(pu[1][cc], vu.v, acc[1][n]);
    }
  }
  __builtin_amdgcn_s_setprio(0);
}

// ---- flash: ring-3 LDS (48KB), prefetch dist 2, vmcnt(4); 1024 blocks ----
// qc=2 is the VGPR-feasible max reuse (qc=4 spilled: R18, 600MB scratch).
__global__ __launch_bounds__(256, 3) void k_flash(
    const uint16_t* __restrict__ Qb, const uint16_t* __restrict__ Kb,
    const uint16_t* __restrict__ VT, uint16_t* __restrict__ Ob) {
  __shared__ uint16_t Ks[3][4096];   // [kv][hd], chunk^(kv&7)
  __shared__ uint16_t Vs[3][4096];   // [hd][kv], chunk^(hd&7)
  const int j = 63 - ((int)blockIdx.x >> 4);   // 32-row q-tile, longest first
  const int gb = blockIdx.x & 15;
  const int g = gb & 7, b = gb >> 3;
  const int tid = threadIdx.x, lane = tid & 63, w = tid >> 6;
  const int l16 = lane & 15, lg = lane >> 4;
  const int h = g * 4 + w;                     // wave's head
  const int qb0 = j * 32;                      // block/wave 32-row q base

  bf16x8 qf[2][2];
#pragma unroll
  for (int qc = 0; qc < 2; ++qc) {
    const size_t tokq = (size_t)b * S_LEN + qb0 + qc * 16 + l16;
    qf[qc][0] = *(const bf16x8*)(Qb + tokq * 2048 + h * 64 + lg * 8);
    qf[qc][1] = *(const bf16x8*)(Qb + tokq * 2048 + h * 64 + 32 + lg * 8);
  }
  bf16x8 onesv;
#pragma unroll
  for (int e = 0; e < 8; ++e) ((__bf16*)&onesv)[e] = (__bf16)1.0f;

  const int srow = tid >> 3, shc = tid & 7;
  const int swz = (shc ^ (srow & 7)) * 8;
  const uint16_t* Kg = Kb + ((size_t)b * S_LEN + srow) * 512 + g * 64 + swz;
  const uint16_t* Vg = VT + ((size_t)(b * 8 + g) * 64 + srow) * S_LEN + swz;

  float m_r[2] = {-1e30f, -1e30f};
  f32x4 lacc[2] = {};
  f32x4 acc[2][4] = {};
  const int nt = (j >> 1) + 1;                 // KV tiles needed

  auto stage = [&](int t, int buf) {
    const size_t kv0 = (size_t)t * 64;
    uint16_t* kd = &Ks[buf][tid * 8];
    uint16_t* vd = &Vs[buf][tid * 8];
    gld16(Kg + kv0 * 512, kd);
    gld16(Kg + (kv0 + 32) * 512, kd + 2048);
    gld16(Vg + kv0, vd);
    gld16(Vg + kv0 + (size_t)32 * S_LEN, vd + 2048);
  };

  stage(0, 0);
  stage(nt > 1 ? 1 : 0, 1);

  int cur = 0;
  for (int t = 0; t < nt; ++t) {
    asm volatile("s_waitcnt vmcnt(4)" ::: "memory");
    __builtin_amdgcn_s_barrier();
    {
      int ts = t + 2 < nt ? t + 2 : nt - 1;
      int bufn = cur + 2; if (bufn >= 3) bufn -= 3;
      stage(ts, bufn);
    }
    if (t == nt - 1)
      tile_compute<true >(Ks[cur], Vs[cur], qf, onesv, l16, lg, t * 64, qb0, m_r, lacc, acc);
    else
      tile_compute<false>(Ks[cur], Vs[cur], qf, onesv, l16, lg, t * 64, qb0, m_r, lacc, acc);
    cur = cur + 1 < 3 ? cur + 1 : 0;
  }
#pragma unroll
  for (int qc = 0; qc < 2; ++qc) {
    float li[4];
#pragma unroll
    for (int r = 0; r < 4; ++r) li[r] = 1.0f / lacc[qc][r];
#pragma unroll
    for (int n = 0; n < 4; ++n)
#pragma unroll
      for (int r = 0; r < 4; ++r) {
        int qo = qb0 + qc * 16 + lg * 4 + r;
        Ob[((size_t)b * S_LEN + qo) * 2048 + h * 64 + n * 16 + l16] =
            f2bf(acc[qc][n][r] * li[r]);
      }
  }
}

extern "C" void kernel_launch(void* const* d_in, const int* in_sizes, int n_in,
                              void* d_out, int out_size, void* d_ws, size_t ws_size,
                              hipStream_t stream) {
  const float* x    = (const float*)d_in[0];
  const float* cosT = (const float*)d_in[1];
  const float* sinT = (const float*)d_in[2];
  const float* wq   = (const float*)d_in[4];
  const float* wk   = (const float*)d_in[5];
  const float* wv   = (const float*)d_in[6];
  const float* wo   = (const float*)d_in[7];
  float* out = (float*)d_out;

  char* ws = (char*)d_ws;
  size_t off = 0;
  auto alloc = [&](size_t bytes) {
    void* p = ws + off;
    off += (bytes + 255) & ~(size_t)255;
    return p;
  };
  uint16_t* xb   = (uint16_t*)alloc((size_t)NTOK * EMB * 2);
  uint16_t* wT   = (uint16_t*)alloc((size_t)3072 * 2048 * 2);
  uint16_t* woT  = (uint16_t*)alloc((size_t)2048 * 2048 * 2);
  uint16_t* qkvb = (uint16_t*)alloc((size_t)NTOK * 3072 * 2);
  uint16_t* qb   = (uint16_t*)alloc((size_t)NTOK * 2048 * 2);
  uint16_t* kb   = (uint16_t*)alloc((size_t)NTOK * 512 * 2);
  uint16_t* vT   = (uint16_t*)alloc((size_t)NTOK * 512 * 2);
  uint16_t* ob   = xb;                 // xb dead after QKV GEMM

  // merged: cvt (8192 blocks) + 4 weight transposes (10240 tile-blocks)
  k_preproc<<<18432, 256, 0, stream>>>(x, xb, wq, wk, wv, wo, wT, woT);

  // QKV: 128x192 tile -> 512 blocks = 2/CU (TLP structure)
  k_gemm128<3, uint16_t><<<512, 256, 0, stream>>>(xb, wT, qkvb, 4096, 3072, 2048);
  k_rope<<<(NTOK * 320) / 256, 256, 0, stream>>>(qkvb, cosT, sinT, qb, kb);
  k_transpose_v<<<dim3(64, 2, 16), 256, 0, stream>>>(qkvb, vT);
  k_flash<<<dim3(1024), 256, 0, stream>>>(qb, kb, vT, ob);
  // out-proj: 128x128 tile, 512 blocks = 2/CU
  k_gemm128<2, float><<<512, 256, 0, stream>>>(ob, woT, out, 4096, 2048, 2048);
}